// Round 2
// baseline (1285.288 us; speedup 1.0000x reference)
//
#include <hip/hip_runtime.h>

// RNN B=256 T=2048 I=64 H=256 — one workgroup per sample, MFMA matvec recurrence.
// Latency/LDS-pipe-bound: wall = 2048 serial steps x per-step critical path.
// R2 change: 8 waves -> 4 waves (wave w owns rows [64w,64w+64), 4 M-tiles each).
//  - halves per-step LDS h-broadcast traffic (32 ds_read_b128 instead of 64);
//    broadcast reads are conflict-free but NOT bandwidth-free, and 8 lockstep
//    waves gave no latency hiding, only pipe contention.
//  - halves barrier width; per-SIMD MFMA issue count unchanged (1x32 vs 2x16).
//  - all 64 lanes own exactly one output row (was n<8 of each wave).
//  - fast_tanh: clamp + exp + v_rcp_f32 (removes exact-div sequence from the
//    serial tail; h is stored f16 so approx rcp is invisible).
// Kept from R1: per-block xp mini-GEMM (timesteps as MFMA columns), kt-parity
// partials (dependent-MFMA depth 4), step loop unrolled x2 for static hbuf ptrs.
// NOTE: no runtime indexing of A-fragment arrays (would spill to scratch).

static constexpr int nB = 256;
static constexpr int nT = 2048;
static constexpr int nI = 64;
static constexpr int nH = 256;
static constexpr int XBLK = 32;     // timesteps of x staged/projected per block
static constexpr int XSTR = 72;     // padded halfword stride of an xbuf row
static constexpr int THREADS = 256; // 4 waves; wave w owns output rows [64w,64w+64)

typedef _Float16 f16x8 __attribute__((ext_vector_type(8)));
typedef _Float16 f16x4 __attribute__((ext_vector_type(4)));
typedef float f32x4 __attribute__((ext_vector_type(4)));

__device__ __forceinline__ float fast_tanh(float x) {
  // tanh(x) = (e^{2x}-1)/(e^{2x}+1); clamp so e^{2x} <= e^16 (no overflow).
  float xc = fminf(8.f, fmaxf(-8.f, x));
  float e  = __expf(2.f * xc);
  return (e - 1.f) * __builtin_amdgcn_rcpf(e + 1.f);
}

__global__ __launch_bounds__(THREADS, 1)
void rnn_mfma(const float* __restrict__ x, const int* __restrict__ lengths,
              const float* __restrict__ Wih, const float* __restrict__ Whh,
              const float* __restrict__ bih, const float* __restrict__ bhh,
              const float* __restrict__ Wfc, const float* __restrict__ bfc,
              float* __restrict__ out)
{
  __shared__ __align__(16) _Float16 hbuf[2][nH];            // 1 KB
  __shared__ __align__(16) _Float16 xbuf[2][XBLK * XSTR];   // 9 KB
  __shared__ float xp[nH][XBLK + 1];                        // 33.8 KB
  __shared__ float red[THREADS / 64];

  const int b   = blockIdx.x;
  const int tid = threadIdx.x;
  const int w   = tid >> 6;       // wave 0..3
  const int l   = tid & 63;
  const int q   = l >> 4;         // quad 0..3
  const int n   = l & 15;         // MFMA column lane
  const int len = lengths[b];     // in [1, nT]
  const float* xb = x + (size_t)b * nT * nI;

  // ---- preamble: pack this wave's W rows into A-fragments (f16)
  // A layout (16x16x32): lane holds A[m = lane&15][k = 8*(lane>>4) + j], j=0..7
  f16x8 Ah[4][8];   // W_hh rows 64w+16mt+n, k = 32kt+8q+j
  f16x8 Ax[4][2];   // W_ih (I=64 -> 2 k-tiles), used only in the xp mini-GEMM
#pragma unroll
  for (int mt = 0; mt < 4; ++mt) {
    const int row = 64 * w + 16 * mt + n;
#pragma unroll
    for (int kt = 0; kt < 8; ++kt) {
      const float* src = Whh + row * nH + 32 * kt + 8 * q;
      f16x8 a;
#pragma unroll
      for (int j = 0; j < 8; ++j) a[j] = (_Float16)src[j];
      Ah[mt][kt] = a;
    }
#pragma unroll
    for (int kt = 0; kt < 2; ++kt) {
      const float* src = Wih + row * nI + 32 * kt + 8 * q;
      f16x8 a;
#pragma unroll
      for (int j = 0; j < 8; ++j) a[j] = (_Float16)src[j];
      Ax[mt][kt] = a;
    }
  }
  // bias in C layout: reg r <-> row 64w + 16mt + 4q + r (folded into xp)
  f32x4 biasC[4];
#pragma unroll
  for (int mt = 0; mt < 4; ++mt)
#pragma unroll
    for (int r = 0; r < 4; ++r) {
      const int r0 = 64 * w + 16 * mt + 4 * q + r;
      biasC[mt][r] = bih[r0] + bhh[r0];
    }
  // every lane owns exactly one output row
  const int mt_sel  = n >> 2;     // 0..3
  const int reg_sel = n & 3;
  const int row_own = 64 * w + 16 * mt_sel + 4 * q + reg_sel;

  // x staging: 2 float4 per thread per block (32 steps x 64 floats = 2048)
  const int offA = tid * 4;
  const int offB = tid * 4 + 1024;
  const int dstA = (offA >> 6) * XSTR + (offA & 63);
  const int dstB = (offB >> 6) * XSTR + (offB & 63);

  // ---- h0 = 0; stage x block 0
  hbuf[0][tid] = (_Float16)0.f;
  {
    float4 vA = *(const float4*)(xb + offA);
    float4 vB = *(const float4*)(xb + offB);
    f16x4 pA = { (_Float16)vA.x, (_Float16)vA.y, (_Float16)vA.z, (_Float16)vA.w };
    f16x4 pB = { (_Float16)vB.x, (_Float16)vB.y, (_Float16)vB.z, (_Float16)vB.w };
    *(f16x4*)(xbuf[0] + dstA) = pA;
    *(f16x4*)(xbuf[0] + dstB) = pB;
  }
  __syncthreads();

  int t = 0;
  for (int blk = 0; t < len; ++blk) {
    float4 preA, preB;
    const bool havepre = ((blk + 1) * XBLK < len);
    if (havepre) {
      const float* nx = xb + (size_t)(blk + 1) * XBLK * nI;
      preA = *(const float4*)(nx + offA);
      preB = *(const float4*)(nx + offB);
    }

    // ---- xp mini-GEMM: xp[row][s] = bias + W_ih . x_{blk*32+s}; timesteps
    // are the MFMA columns (ct=0 -> s=n, ct=1 -> s=16+n).
    {
      const _Float16* xB = xbuf[blk & 1];
      f32x4 g0[4], g1[4];
#pragma unroll
      for (int mt = 0; mt < 4; ++mt) { g0[mt] = biasC[mt]; g1[mt] = biasC[mt]; }
#pragma unroll
      for (int kt = 0; kt < 2; ++kt) {
        f16x8 B0 = *(const f16x8*)(xB + n * XSTR + 32 * kt + 8 * q);
        f16x8 B1 = *(const f16x8*)(xB + (16 + n) * XSTR + 32 * kt + 8 * q);
#pragma unroll
        for (int mt = 0; mt < 4; ++mt) {
          g0[mt] = __builtin_amdgcn_mfma_f32_16x16x32_f16(Ax[mt][kt], B0, g0[mt], 0, 0, 0);
          g1[mt] = __builtin_amdgcn_mfma_f32_16x16x32_f16(Ax[mt][kt], B1, g1[mt], 0, 0, 0);
        }
      }
#pragma unroll
      for (int mt = 0; mt < 4; ++mt)
#pragma unroll
        for (int r = 0; r < 4; ++r) {
          const int r0 = 64 * w + 16 * mt + 4 * q + r;
          xp[r0][n]      = g0[mt][r];
          xp[r0][16 + n] = g1[mt][r];
        }
    }
    __syncthreads();

    const int nsteps = min(XBLK, len - blk * XBLK);

    auto step = [&](int s, const _Float16* hsrc, _Float16* hdst) {
      float xpv = xp[row_own][s];   // 2-way aliased read: free
      f32x4 z = {0.f, 0.f, 0.f, 0.f};
      f32x4 pe[4] = {z, z, z, z}, po[4] = {z, z, z, z};  // kt-parity partials
#pragma unroll
      for (int i = 0; i < 4; ++i) {
        f16x8 Ba = *(const f16x8*)(hsrc + 64 * i + 8 * q);        // kt = 2i
        f16x8 Bb = *(const f16x8*)(hsrc + 64 * i + 32 + 8 * q);   // kt = 2i+1
#pragma unroll
        for (int mt = 0; mt < 4; ++mt) {
          pe[mt] = __builtin_amdgcn_mfma_f32_16x16x32_f16(Ah[mt][2 * i],     Ba, pe[mt], 0, 0, 0);
          po[mt] = __builtin_amdgcn_mfma_f32_16x16x32_f16(Ah[mt][2 * i + 1], Bb, po[mt], 0, 0, 0);
        }
      }
      // owned-value extraction: sum parities, select mt (2 bits), select reg (2 bits)
      f32x4 s0 = pe[0] + po[0], s1 = pe[1] + po[1];
      f32x4 s2 = pe[2] + po[2], s3 = pe[3] + po[3];
      f32x4 ma = (mt_sel & 1) ? s1 : s0;
      f32x4 mb = (mt_sel & 1) ? s3 : s2;
      f32x4 c  = (mt_sel & 2) ? mb : ma;
      float lo = (reg_sel & 1) ? c[1] : c[0];
      float hi = (reg_sel & 1) ? c[3] : c[2];
      float v  = ((reg_sel & 2) ? hi : lo) + xpv;
      float hn = fast_tanh(v);

      // fold next-x writeback in before this block's final barrier
      if (s == nsteps - 1 && havepre) {
        f16x4 pA = { (_Float16)preA.x, (_Float16)preA.y, (_Float16)preA.z, (_Float16)preA.w };
        f16x4 pB = { (_Float16)preB.x, (_Float16)preB.y, (_Float16)preB.z, (_Float16)preB.w };
        _Float16* d = xbuf[(blk + 1) & 1];
        *(f16x4*)(d + dstA) = pA;
        *(f16x4*)(d + dstB) = pB;
      }
      hdst[row_own] = (_Float16)hn;   // all 64 lanes write one row each
      __syncthreads();
    };

    // t parity == s parity (blk*XBLK even): unroll x2 with static buffers
    int s = 0;
    for (; s + 2 <= nsteps; s += 2) {
      step(s,     hbuf[0], hbuf[1]);
      step(s + 1, hbuf[1], hbuf[0]);
    }
    if (s < nsteps) step(s, hbuf[0], hbuf[1]);
    t += nsteps;
  }

  // ---- epilogue: out[b] = h_final . W_fc + b_fc
  float v = (float)hbuf[len & 1][tid] * Wfc[tid];
#pragma unroll
  for (int off = 32; off; off >>= 1) v += __shfl_down(v, off);
  if (l == 0) red[w] = v;
  __syncthreads();
  if (tid == 0) {
    float acc = bfc[0];
#pragma unroll
    for (int i = 0; i < THREADS / 64; ++i) acc += red[i];
    out[b] = acc;
  }
}

extern "C" void kernel_launch(void* const* d_in, const int* in_sizes, int n_in,
                              void* d_out, int out_size, void* d_ws, size_t ws_size,
                              hipStream_t stream) {
  const float* x   = (const float*)d_in[0];
  const int* lens  = (const int*)d_in[1];
  const float* Wih = (const float*)d_in[2];
  const float* Whh = (const float*)d_in[3];
  const float* bih = (const float*)d_in[4];
  const float* bhh = (const float*)d_in[5];
  const float* Wfc = (const float*)d_in[6];
  const float* bfc = (const float*)d_in[7];
  float* out = (float*)d_out;

  rnn_mfma<<<nB, THREADS, 0, stream>>>(x, lens, Wih, Whh, bih, bhh, Wfc, bfc, out);
}

// Round 3
// 1080.362 us; speedup vs baseline: 1.1897x; 1.1897x over previous
//
#include <hip/hip_runtime.h>

// RNN B=256 T=2048 I=64 H=256 — one workgroup per sample, MFMA matvec recurrence.
// Serial-latency-bound: wall = 2048 steps x per-step critical path.
// R3 = revert to R1's 8-wave structure (R2's 4-wave/1-per-SIMD lost ~250cy/step
// of cross-wave latency hiding; LDS broadcast reads were NOT the bottleneck), plus:
//  - next-block x prefetch issued AFTER the mini-GEMM barrier: first vmcnt(0)
//    drain is then a full step (~1150cy) after issue -> 900cy HBM latency fully
//    hidden (was ~400-600cy exposed once per 32 steps).
//  - s_setprio(1) around the ds_read+MFMA region (T5; cheap, possibly null).
//  - tanh with v_rcp instead of exact division (h is f16; rcp error invisible).
// Kept from R1: 8 waves own 32 rows each, per-block xp mini-GEMM (timesteps as
// MFMA columns), kt-parity partials (dependent-MFMA depth 4), x2 step unroll.

static constexpr int nB = 256;
static constexpr int nT = 2048;
static constexpr int nI = 64;
static constexpr int nH = 256;
static constexpr int XBLK = 32;     // timesteps of x staged/projected per block
static constexpr int XSTR = 72;     // padded halfword stride of an xbuf row
static constexpr int THREADS = 512; // 8 waves; wave w owns output rows [32w,32w+32)

typedef _Float16 f16x8 __attribute__((ext_vector_type(8)));
typedef _Float16 f16x4 __attribute__((ext_vector_type(4)));
typedef float f32x4 __attribute__((ext_vector_type(4)));

__device__ __forceinline__ float fast_tanh(float x) {
  float a = fabsf(x);
  float e = __expf(-2.0f * a);           // in (0,1], never overflows
  float r = (1.0f - e) * __builtin_amdgcn_rcpf(1.0f + e);
  return copysignf(r, x);
}

__global__ __launch_bounds__(THREADS, 2)
void rnn_mfma(const float* __restrict__ x, const int* __restrict__ lengths,
              const float* __restrict__ Wih, const float* __restrict__ Whh,
              const float* __restrict__ bih, const float* __restrict__ bhh,
              const float* __restrict__ Wfc, const float* __restrict__ bfc,
              float* __restrict__ out)
{
  __shared__ __align__(16) _Float16 hbuf[2][nH];            // 1 KB
  __shared__ __align__(16) _Float16 xbuf[2][XBLK * XSTR];   // 9 KB
  __shared__ float xp[nH][XBLK + 1];                        // 33.8 KB
  __shared__ float red[THREADS / 64];

  const int b   = blockIdx.x;
  const int tid = threadIdx.x;
  const int w   = tid >> 6;       // wave 0..7
  const int l   = tid & 63;
  const int q   = l >> 4;         // quad 0..3
  const int n   = l & 15;         // MFMA column lane
  const int len = lengths[b];     // in [1, nT]
  const float* xb = x + (size_t)b * nT * nI;

  // ---- preamble: pack this wave's W rows into A-fragments (f16)
  // A layout (16x16x32): lane holds A[m = lane&15][k = 8*(lane>>4) + j], j=0..7
  f16x8 Ah[2][8];   // W_hh rows 32w+16mt+n, k = 32kt+8q+j
  f16x8 Ax[2][2];   // W_ih (I=64 -> 2 k-tiles), used only in the xp mini-GEMM
#pragma unroll
  for (int mt = 0; mt < 2; ++mt) {
    const int row = 32 * w + 16 * mt + n;
#pragma unroll
    for (int kt = 0; kt < 8; ++kt) {
      const float* src = Whh + row * nH + 32 * kt + 8 * q;
      f16x8 a;
#pragma unroll
      for (int j = 0; j < 8; ++j) a[j] = (_Float16)src[j];
      Ah[mt][kt] = a;
    }
#pragma unroll
    for (int kt = 0; kt < 2; ++kt) {
      const float* src = Wih + row * nI + 32 * kt + 8 * q;
      f16x8 a;
#pragma unroll
      for (int j = 0; j < 8; ++j) a[j] = (_Float16)src[j];
      Ax[mt][kt] = a;
    }
  }
  // bias in C layout: reg r <-> row 32w + 16mt + 4q + r (folded into xp)
  f32x4 biasC[2];
#pragma unroll
  for (int r = 0; r < 4; ++r) {
    const int r0 = 32 * w + 4 * q + r;
    biasC[0][r] = bih[r0] + bhh[r0];
    biasC[1][r] = bih[r0 + 16] + bhh[r0 + 16];
  }
  // column-split ownership: lanes n<8 each finish exactly one output row
  const int mt_sel  = (n >> 2) & 1;
  const int reg_sel = n & 3;
  const int row_own = 32 * w + 16 * mt_sel + 4 * q + reg_sel;

  // x staging geometry: thread writes 4 halfs at (row, col) of the block
  const int xoff = ((tid * 4) >> 6) * XSTR + ((tid * 4) & 63);

  // ---- h0 = 0; stage x block 0
  if (tid < nH) hbuf[0][tid] = (_Float16)0.f;
  {
    float4 v = *(const float4*)(xb + tid * 4);
    f16x4 pv = { (_Float16)v.x, (_Float16)v.y, (_Float16)v.z, (_Float16)v.w };
    *(f16x4*)(xbuf[0] + xoff) = pv;
  }
  __syncthreads();

  int t = 0;
  for (int blk = 0; t < len; ++blk) {
    // ---- xp mini-GEMM: xp[row][s] = bias + W_ih . x_{blk*32+s}; timesteps
    // are the MFMA columns (ct=0 -> s=n, ct=1 -> s=16+n).
    {
      const _Float16* xB = xbuf[blk & 1];
      f32x4 g00 = biasC[0], g01 = biasC[0], g10 = biasC[1], g11 = biasC[1];
#pragma unroll
      for (int kt = 0; kt < 2; ++kt) {
        f16x8 B0 = *(const f16x8*)(xB + n * XSTR + 32 * kt + 8 * q);         // ct=0
        f16x8 B1 = *(const f16x8*)(xB + (16 + n) * XSTR + 32 * kt + 8 * q);  // ct=1
        g00 = __builtin_amdgcn_mfma_f32_16x16x32_f16(Ax[0][kt], B0, g00, 0, 0, 0);
        g10 = __builtin_amdgcn_mfma_f32_16x16x32_f16(Ax[1][kt], B0, g10, 0, 0, 0);
        g01 = __builtin_amdgcn_mfma_f32_16x16x32_f16(Ax[0][kt], B1, g01, 0, 0, 0);
        g11 = __builtin_amdgcn_mfma_f32_16x16x32_f16(Ax[1][kt], B1, g11, 0, 0, 0);
      }
#pragma unroll
      for (int r = 0; r < 4; ++r) {
        const int r0 = 32 * w + 4 * q + r;
        xp[r0][n]           = g00[r];
        xp[r0 + 16][n]      = g10[r];
        xp[r0][16 + n]      = g01[r];
        xp[r0 + 16][16 + n] = g11[r];
      }
    }
    __syncthreads();

    // ---- issue next-block x prefetch AFTER the mini-GEMM barrier: the first
    // implicit vmcnt(0) drain is step 0's barrier, ~1 full step after issue,
    // so the ~900cy HBM latency is fully hidden.
    float4 pre;
    const bool havepre = ((blk + 1) * XBLK < len);
    if (havepre)
      pre = *(const float4*)(xb + (size_t)(blk + 1) * XBLK * nI + tid * 4);

    const int nsteps = min(XBLK, len - blk * XBLK);

    auto step = [&](int s, const _Float16* hsrc, _Float16* hdst) {
      float xpv = xp[row_own][s];   // conflict-free; latency hides under MFMA
      __builtin_amdgcn_s_setprio(1);
      f32x4 z = {0.f, 0.f, 0.f, 0.f};
      f32x4 p00 = z, p01 = z, p10 = z, p11 = z;  // kt-parity partials: depth 4
#pragma unroll
      for (int kt = 0; kt < 8; kt += 2) {
        f16x8 Be = *(const f16x8*)(hsrc + 32 * kt + 8 * q);
        f16x8 Bo = *(const f16x8*)(hsrc + 32 * (kt + 1) + 8 * q);
        p00 = __builtin_amdgcn_mfma_f32_16x16x32_f16(Ah[0][kt],     Be, p00, 0, 0, 0);
        p10 = __builtin_amdgcn_mfma_f32_16x16x32_f16(Ah[1][kt],     Be, p10, 0, 0, 0);
        p01 = __builtin_amdgcn_mfma_f32_16x16x32_f16(Ah[0][kt + 1], Bo, p01, 0, 0, 0);
        p11 = __builtin_amdgcn_mfma_f32_16x16x32_f16(Ah[1][kt + 1], Bo, p11, 0, 0, 0);
      }
      __builtin_amdgcn_s_setprio(0);
      f32x4 s0 = p00 + p01;
      f32x4 s1 = p10 + p11;
      float lo0 = (reg_sel & 1) ? s0[1] : s0[0];
      float hi0 = (reg_sel & 1) ? s0[3] : s0[2];
      float v0  = (reg_sel & 2) ? hi0 : lo0;
      float lo1 = (reg_sel & 1) ? s1[1] : s1[0];
      float hi1 = (reg_sel & 1) ? s1[3] : s1[2];
      float v1  = (reg_sel & 2) ? hi1 : lo1;
      float v   = (mt_sel ? v1 : v0) + xpv;
      float hn  = fast_tanh(v);

      // fold next-x writeback in before this block's final barrier
      if (s == nsteps - 1 && havepre) {
        f16x4 pv = { (_Float16)pre.x, (_Float16)pre.y, (_Float16)pre.z, (_Float16)pre.w };
        *(f16x4*)(xbuf[(blk + 1) & 1] + xoff) = pv;
      }
      if (n < 8) hdst[row_own] = (_Float16)hn;
      __syncthreads();
    };

    // t parity == s parity (blk*XBLK even): unroll x2 with static buffers
    int s = 0;
    for (; s + 2 <= nsteps; s += 2) {
      step(s,     hbuf[0], hbuf[1]);
      step(s + 1, hbuf[1], hbuf[0]);
    }
    if (s < nsteps) step(s, hbuf[0], hbuf[1]);
    t += nsteps;
  }

  // ---- epilogue: out[b] = h_final . W_fc + b_fc
  float v = 0.f;
  if (tid < nH) v = (float)hbuf[len & 1][tid] * Wfc[tid];
#pragma unroll
  for (int off = 32; off; off >>= 1) v += __shfl_down(v, off);
  if (l == 0) red[w] = v;
  __syncthreads();
  if (tid == 0) {
    float acc = bfc[0];
#pragma unroll
    for (int i = 0; i < THREADS / 64; ++i) acc += red[i];
    out[b] = acc;
  }
}

extern "C" void kernel_launch(void* const* d_in, const int* in_sizes, int n_in,
                              void* d_out, int out_size, void* d_ws, size_t ws_size,
                              hipStream_t stream) {
  const float* x   = (const float*)d_in[0];
  const int* lens  = (const int*)d_in[1];
  const float* Wih = (const float*)d_in[2];
  const float* Whh = (const float*)d_in[3];
  const float* bih = (const float*)d_in[4];
  const float* bhh = (const float*)d_in[5];
  const float* Wfc = (const float*)d_in[6];
  const float* bfc = (const float*)d_in[7];
  float* out = (float*)d_out;

  rnn_mfma<<<nB, THREADS, 0, stream>>>(x, lens, Wih, Whh, bih, bhh, Wfc, bfc, out);
}